// Round 5
// baseline (3021.185 us; speedup 1.0000x reference)
//
#include <hip/hip_runtime.h>
#include <hip/hip_bf16.h>
#include <math.h>

#define BATCH 256
#define DIM 1024
#define KG 7
#define VOCAB 32000
#define NIT 26   // 0.64^25 * ||z1|| < 3e-3 elementwise; ref early-exit delta far below tol

typedef short bf16x8 __attribute__((ext_vector_type(8)));
typedef float f32x4 __attribute__((ext_vector_type(4)));

__device__ __forceinline__ int iclamp(int v, int lo, int hi) { return v < lo ? lo : (v > hi ? hi : v); }
__device__ __forceinline__ unsigned short rneb(float f) {
    unsigned u = __float_as_uint(f);
    return (unsigned short)((u + 0x7FFFu + ((u >> 16) & 1u)) >> 16);
}
__device__ __forceinline__ float bftof(unsigned short s) { return __uint_as_float(((unsigned)s) << 16); }

__device__ __forceinline__ bf16x8 pack8(const float* __restrict__ p) {
    float4 a = *reinterpret_cast<const float4*>(p);
    float4 b = *reinterpret_cast<const float4*>(p + 4);
    union { short s[8]; bf16x8 v; } r;
    r.s[0] = (short)rneb(a.x); r.s[1] = (short)rneb(a.y);
    r.s[2] = (short)rneb(a.z); r.s[3] = (short)rneb(a.w);
    r.s[4] = (short)rneb(b.x); r.s[5] = (short)rneb(b.y);
    r.s[6] = (short)rneb(b.z); r.s[7] = (short)rneb(b.w);
    return r.v;
}

// ---------------- block reduce (256 threads, 4 waves) ----------------
__device__ __forceinline__ float block_reduce(float v, float* sm) {
    #pragma unroll
    for (int o = 32; o > 0; o >>= 1) v += __shfl_down(v, o, 64);
    int wid = threadIdx.x >> 6, lane = threadIdx.x & 63;
    if (lane == 0) sm[wid] = v;
    __syncthreads();
    if (threadIdx.x == 0) sm[0] = sm[0] + sm[1] + sm[2] + sm[3];
    __syncthreads();
    float r = sm[0];
    __syncthreads();
    return r;
}

// ---------------- addr row inverse norms ----------------
__global__ void addr_norm_k(const float* __restrict__ addr, float* __restrict__ addr_inv) {
    __shared__ float sm[4];
    for (int k = 0; k < KG; k++) {
        float s = 0.f;
        for (int d = threadIdx.x; d < DIM; d += 256) { float a = addr[k * DIM + d]; s += a * a; }
        float tot = block_reduce(s, sm);
        if (threadIdx.x == 0) addr_inv[k] = 1.0f / fmaxf(sqrtf(tot), 1e-12f);
        __syncthreads();
    }
}

// ---------------- per-sample: f_emb, xcat(h,f) f32+bf16, scores->pi, idx, gamma ----------------
__global__ void sample_k(const float* __restrict__ h, const float* __restrict__ fib_s,
                         const float* __restrict__ fib_e, const int* __restrict__ tok,
                         const float* __restrict__ opemb, const float* __restrict__ num_w,
                         const float* __restrict__ num_b, const float* __restrict__ addr,
                         const float* __restrict__ fs_w, const float* __restrict__ fs_b,
                         const float* __restrict__ fe_w, const float* __restrict__ fe_b,
                         const float* __restrict__ c1w, const float* __restrict__ c1b,
                         const float* __restrict__ c2w, const float* __restrict__ c2b,
                         const float* __restrict__ addr_inv, float* __restrict__ xcat,
                         unsigned short* __restrict__ xbf,
                         float* __restrict__ gamma_ws, int* __restrict__ kidx,
                         float* __restrict__ pi_out) {
    int b = blockIdx.x;
    int t = tok[b];
    bool ctrl = (t < 7);
    int tcl = iclamp(t, 0, 6);
    float numv = (float)t - 7.0f;
    float fsv = fib_s[b], fev = fib_e[b];
    float vv = 0.f, dot[KG];
    #pragma unroll
    for (int k = 0; k < KG; k++) dot[k] = 0.f;
    for (int d = threadIdx.x; d < DIM; d += 256) {
        float femb = tanhf(fsv * fs_w[d] + fs_b[d] + fev * fe_w[d] + fe_b[d]);
        float hf = h[b * DIM + d];
        xcat[b * 2048 + d] = hf;
        xcat[b * 2048 + DIM + d] = femb;
        xbf[b * 2048 + d] = rneb(hf);
        xbf[b * 2048 + DIM + d] = rneb(femb);
        float v;
        if (ctrl) v = opemb[tcl * DIM + d];
        else      v = numv * num_w[d] + num_b[d] + femb;
        vv += v * v;
        #pragma unroll
        for (int k = 0; k < KG; k++) dot[k] += v * addr[k * DIM + d];
    }
    __shared__ float sm[4];
    vv = block_reduce(vv, sm);
    float sc[KG];
    for (int k = 0; k < KG; k++) sc[k] = block_reduce(dot[k], sm);
    if (threadIdx.x == 0) {
        float inv_v = 1.0f / fmaxf(sqrtf(vv), 1e-12f);
        float m = -1e30f;
        for (int k = 0; k < KG; k++) { sc[k] = 5.0f * sc[k] * inv_v * addr_inv[k]; m = fmaxf(m, sc[k]); }
        float se = 0.f, p[KG];
        for (int k = 0; k < KG; k++) { p[k] = expf(sc[k] - m); se += p[k]; }
        float ent = 0.f, best = -1.f;
        int idx = 0;
        for (int k = 0; k < KG; k++) {
            p[k] /= se;
            ent -= p[k] * logf(p[k] + 1e-8f);
            if (p[k] > best) { best = p[k]; idx = k; }
        }
        float acc = c2b[0];
        for (int j = 0; j < 16; j++) {
            float x = fmaxf(0.0f, ent * c1w[j * 2 + 0] + c1b[j]);
            acc += x * c2w[j];
        }
        float g = (acc > 20.f) ? acc : log1pf(expf(acc));
        gamma_ws[b] = g;
        kidx[b] = idx;
        for (int k = 0; k < KG; k++) pi_out[b * KG + k] = p[k];
    }
}

// ---------------- group samples by expert ----------------
__global__ void group_k(const int* __restrict__ kidx, int* __restrict__ order,
                        int* __restrict__ ebase, int* __restrict__ ecnt,
                        int* __restrict__ arrive) {
    __shared__ int kk[BATCH];
    __shared__ int cnt[KG];
    __shared__ int bs[KG];
    int tid = threadIdx.x;
    kk[tid] = iclamp(kidx[tid], 0, 6);
    __syncthreads();
    if (tid < KG) { int c = 0; for (int i = 0; i < BATCH; i++) c += (kk[i] == tid); cnt[tid] = c; }
    __syncthreads();
    if (tid == 0) { int s = 0; for (int k = 0; k < KG; k++) { bs[k] = s; s += cnt[k]; } }
    __syncthreads();
    int mk = kk[tid];
    int rank = 0;
    for (int i = 0; i < tid; i++) rank += (kk[i] == mk);
    order[bs[mk] + rank] = tid;
    if (tid < KG) { ebase[tid] = bs[tid]; ecnt[tid] = cnt[tid]; arrive[tid] = 0; }
}

// ---- stage a 1024x64 f32 slice -> LDS bf16 Wt3[g=128][c=64][j=8] ----
__device__ __forceinline__ void stage64(const float* __restrict__ src, unsigned short* wt,
                                        int c0, int tid) {
    int c = tid & 63, gs = tid >> 6;
    #pragma unroll 2
    for (int gp = 0; gp < 32; gp++) {
        int g = gp * 4 + gs;
        int d = g * 8;
        union { short s[8]; bf16x8 v; } u;
        #pragma unroll
        for (int j = 0; j < 8; j++) {
            float f = src[(size_t)(d + j) * DIM + c0 + c];
            u.s[j] = (short)rneb(f);
        }
        *reinterpret_cast<bf16x8*>(wt + g * 512 + c * 8) = u.v;
    }
}

// ---- K=1024 MFMA loop: ap points at A row (incl. quad*8 offset), wtp at LDS frag base ----
__device__ __forceinline__ f32x4 kloop(const unsigned short* __restrict__ ap,
                                       const unsigned short* wtp, f32x4 acc) {
    #pragma unroll 8
    for (int ch = 0; ch < 32; ch++) {
        bf16x8 a = *reinterpret_cast<const bf16x8*>(ap + ch * 32);
        bf16x8 b = *reinterpret_cast<const bf16x8*>(wtp + ch * 2048);
        acc = __builtin_amdgcn_mfma_f32_16x16x32_bf16(a, b, acc, 0, 0, 0);
    }
    return acc;
}

// ---------------- fused DEQ: c = h@U[k] + f@V[k]; z = f^NIT(0) ----------------
// Grid: 7 experts x 16 col-slices (64 cols). W-slice lives in LDS across all iterations.
__global__ __launch_bounds__(256) void deq_k(
    const unsigned short* __restrict__ xbf,
    const float* __restrict__ Um, const float* __restrict__ Vm, const float* __restrict__ Wm,
    float* __restrict__ c_buf, unsigned short* __restrict__ z_a, unsigned short* __restrict__ z_b,
    const int* __restrict__ order, const int* __restrict__ ebase,
    const int* __restrict__ ecnt, int* __restrict__ arrive) {
    extern __shared__ char ldsraw[];
    unsigned short* wt = (unsigned short*)ldsraw;     // 128 KiB
    int* rowsl = (int*)(ldsraw + 131072);             // 256 ints
    const int kx = blockIdx.x >> 4;
    const int sl = blockIdx.x & 15;
    const int c0 = sl << 6;
    int cnt = iclamp(ecnt[kx], 0, 256);
    if (cnt == 0) return;
    int base = iclamp(ebase[kx], 0, 255);
    int tiles = (cnt + 15) >> 4;
    const int tid = threadIdx.x;
    for (int i = tid; i < tiles * 16; i += 256)
        rowsl[i] = iclamp(order[iclamp(base + min(i, cnt - 1), 0, 255)], 0, 255);
    const int lane = tid & 63, wv = tid >> 6;
    const int n15 = lane & 15, quad = lane >> 4;

    // ---------- phase 1a: partial c = h @ U[k] ----------
    __syncthreads();
    stage64(Um + (size_t)kx * DIM * DIM, wt, c0, tid);
    __syncthreads();
    for (int u = wv; u < tiles * 4; u += 4) {
        int rt = u >> 2, nt = u & 3;
        int ra = rowsl[rt * 16 + n15];
        const unsigned short* ap = xbf + (size_t)ra * 2048 + quad * 8;
        const unsigned short* wtp = wt + quad * 512 + (nt * 16 + n15) * 8;
        f32x4 acc = {0.f, 0.f, 0.f, 0.f};
        acc = kloop(ap, wtp, acc);
        int col = c0 + nt * 16 + n15;
        #pragma unroll
        for (int j = 0; j < 4; j++) {
            int slot = rt * 16 + quad * 4 + j;
            if (slot < cnt) c_buf[(size_t)rowsl[slot] * DIM + col] = acc[j];
        }
    }
    // ---------- phase 1b: c += f @ V[k] ----------
    __syncthreads();
    stage64(Vm + (size_t)kx * DIM * DIM, wt, c0, tid);
    __syncthreads();
    for (int u = wv; u < tiles * 4; u += 4) {
        int rt = u >> 2, nt = u & 3;
        int ra = rowsl[rt * 16 + n15];
        const unsigned short* ap = xbf + (size_t)ra * 2048 + 1024 + quad * 8;
        const unsigned short* wtp = wt + quad * 512 + (nt * 16 + n15) * 8;
        f32x4 acc = {0.f, 0.f, 0.f, 0.f};
        acc = kloop(ap, wtp, acc);
        int col = c0 + nt * 16 + n15;
        #pragma unroll
        for (int j = 0; j < 4; j++) {
            int slot = rt * 16 + quad * 4 + j;
            if (slot < cnt) c_buf[(size_t)rowsl[slot] * DIM + col] += acc[j];
        }
    }
    // ---------- phase 2: stage W once, iterate ----------
    __syncthreads();
    stage64(Wm + (size_t)kx * DIM * DIM, wt, c0, tid);
    __syncthreads();
    for (int it = 0; it < NIT; it++) {
        const unsigned short* zr = (it & 1) ? z_a : z_b;  // it>=1: previous iter's output
        unsigned short* zw = (it & 1) ? z_b : z_a;
        for (int u = wv; u < tiles * 4; u += 4) {
            int rt = u >> 2, nt = u & 3;
            f32x4 acc = {0.f, 0.f, 0.f, 0.f};
            if (it > 0) {
                int ra = rowsl[rt * 16 + n15];
                const unsigned short* ap = zr + (size_t)ra * DIM + quad * 8;
                const unsigned short* wtp = wt + quad * 512 + (nt * 16 + n15) * 8;
                acc = kloop(ap, wtp, acc);
            }
            int col = c0 + nt * 16 + n15;
            #pragma unroll
            for (int j = 0; j < 4; j++) {
                int slot = rt * 16 + quad * 4 + j;
                if (slot < cnt) {
                    int r = rowsl[slot];
                    float v = tanhf(c_buf[(size_t)r * DIM + col] + acc[j]);
                    zw[(size_t)r * DIM + col] = rneb(v);
                }
            }
        }
        if (it < NIT - 1) {
            __threadfence();      // flush my z stores to device scope
            __syncthreads();
            if (tid == 0) {
                __hip_atomic_fetch_add(&arrive[kx], 1, __ATOMIC_RELEASE, __HIP_MEMORY_SCOPE_AGENT);
                int target = 16 * (it + 1);
                while (__hip_atomic_load(&arrive[kx], __ATOMIC_ACQUIRE, __HIP_MEMORY_SCOPE_AGENT) < target)
                    __builtin_amdgcn_s_sleep(2);
            }
            __syncthreads();
            __threadfence();      // invalidate caches before reading other blocks' z
        }
    }
}

// ---------------- linear (f32 SIMT, for stab1/stab2) ----------------
__global__ __launch_bounds__(256) void lin_k(const float* __restrict__ Abuf, int lda,
                                             const float* __restrict__ Wt, int Kdim,
                                             const float* __restrict__ bias,
                                             float* __restrict__ out_f,
                                             int N, int act) {
    int n0 = blockIdx.x * 128;
    int m0 = blockIdx.y * 16;
    __shared__ float As[16][33];
    __shared__ float Bs[32][129];
    int tid = threadIdx.x;
    int tr = tid >> 5, tc = tid & 31;
    float acc[2][4] = {};
    for (int k0 = 0; k0 < Kdim; k0 += 32) {
        {
            int e = tid;
            #pragma unroll
            for (int rep = 0; rep < 2; rep++) {
                int i = e >> 5, kx = e & 31;
                As[i][kx] = Abuf[(size_t)(m0 + i) * lda + k0 + kx];
                e += 256;
            }
        }
        {
            #pragma unroll
            for (int rep = 0; rep < 16; rep++) {
                int e = tid + rep * 256;
                int o = e >> 5, ix = e & 31;
                Bs[ix][o] = Wt[(size_t)(n0 + o) * Kdim + k0 + ix];
            }
        }
        __syncthreads();
        #pragma unroll
        for (int kx = 0; kx < 32; kx++) {
            float a0 = As[tr][kx], a1 = As[tr + 8][kx];
            float b0 = Bs[kx][tc], b1 = Bs[kx][tc + 32], b2v = Bs[kx][tc + 64], b3 = Bs[kx][tc + 96];
            acc[0][0] += a0 * b0; acc[0][1] += a0 * b1; acc[0][2] += a0 * b2v; acc[0][3] += a0 * b3;
            acc[1][0] += a1 * b0; acc[1][1] += a1 * b1; acc[1][2] += a1 * b2v; acc[1][3] += a1 * b3;
        }
        __syncthreads();
    }
    #pragma unroll
    for (int ii = 0; ii < 2; ii++) {
        int m = m0 + tr + ii * 8;
        #pragma unroll
        for (int j = 0; j < 4; j++) {
            int n = n0 + tc + j * 32;
            float v = acc[ii][j] + bias[n];
            if (act == 1) v = tanhf(v);
            else if (act == 2) v = 1.0f / (1.0f + expf(-v));
            out_f[(size_t)m * N + n] = v;
        }
    }
}

// ---------------- h_next ----------------
__global__ void hnext_k(const float* __restrict__ xcat, const float* __restrict__ alocal,
                        const unsigned short* __restrict__ zfin, const float* __restrict__ gamma_ws,
                        float* __restrict__ out_h) {
    int i = blockIdx.x * 256 + threadIdx.x;
    int b = i >> 10, d = i & 1023;
    out_h[i] = xcat[b * 2048 + d] + gamma_ws[b] * alocal[i] * bftof(zfin[i]);
}

// ---------------- decoder: logits = h_next @ dec_w^T + dec_b (MFMA, weights fetched once) ----------------
__global__ __launch_bounds__(256) void dec_k(const float* __restrict__ hn,
                                             const float* __restrict__ dw,
                                             const float* __restrict__ db,
                                             float* __restrict__ out) {
    int n0 = blockIdx.x * 64;
    int tid = threadIdx.x, lane = tid & 63, wv = tid >> 6;
    int n15 = lane & 15, quad = lane >> 4;
    int mbase = wv * 64;
    f32x4 acc[4][4] = {};
    for (int ch = 0; ch < 32; ch++) {
        int k0 = ch * 32 + quad * 8;
        bf16x8 bfr[4], afr[4];
        #pragma unroll
        for (int nt = 0; nt < 4; nt++)
            bfr[nt] = pack8(dw + (size_t)(n0 + nt * 16 + n15) * DIM + k0);
        #pragma unroll
        for (int mt = 0; mt < 4; mt++)
            afr[mt] = pack8(hn + (size_t)(mbase + mt * 16 + n15) * DIM + k0);
        #pragma unroll
        for (int mt = 0; mt < 4; mt++)
            #pragma unroll
            for (int nt = 0; nt < 4; nt++)
                acc[mt][nt] = __builtin_amdgcn_mfma_f32_16x16x32_bf16(afr[mt], bfr[nt], acc[mt][nt], 0, 0, 0);
    }
    #pragma unroll
    for (int mt = 0; mt < 4; mt++)
        #pragma unroll
        for (int nt = 0; nt < 4; nt++) {
            int col = n0 + nt * 16 + n15;
            float bv = db[col];
            #pragma unroll
            for (int j = 0; j < 4; j++) {
                int row = mbase + mt * 16 + quad * 4 + j;
                out[(size_t)row * VOCAB + col] = acc[mt][nt][j] + bv;
            }
        }
}

extern "C" void kernel_launch(void* const* d_in, const int* in_sizes, int n_in,
                              void* d_out, int out_size, void* d_ws, size_t ws_size,
                              hipStream_t stream) {
    const float* h     = (const float*)d_in[0];
    const float* fib_s = (const float*)d_in[1];
    const float* fib_e = (const float*)d_in[2];
    const int*   tok   = (const int*)d_in[3];
    const float* opemb = (const float*)d_in[4];
    const float* num_w = (const float*)d_in[5];
    const float* num_b = (const float*)d_in[6];
    const float* addr  = (const float*)d_in[7];
    const float* Wm    = (const float*)d_in[8];
    const float* Um    = (const float*)d_in[9];
    const float* Vm    = (const float*)d_in[10];
    const float* fs_w  = (const float*)d_in[11];
    const float* fs_b  = (const float*)d_in[12];
    const float* fe_w  = (const float*)d_in[13];
    const float* fe_b  = (const float*)d_in[14];
    const float* s1w   = (const float*)d_in[15];
    const float* s1b   = (const float*)d_in[16];
    const float* s2w   = (const float*)d_in[17];
    const float* s2b   = (const float*)d_in[18];
    const float* c1w   = (const float*)d_in[19];
    const float* c1b   = (const float*)d_in[20];
    const float* c2w   = (const float*)d_in[21];
    const float* c2b   = (const float*)d_in[22];
    const float* dec_w = (const float*)d_in[23];
    const float* dec_b = (const float*)d_in[24];

    float* out_h      = (float*)d_out;
    float* out_logits = out_h + BATCH * DIM;
    float* out_pi     = out_h + BATCH * DIM + (size_t)BATCH * VOCAB;

    // Scratch in the logits region (write-before-read; dec_k overwrites it all last).
    float* scr = out_logits;
    float* xcat   = scr;                                    // 256x2048 f32
    float* c_buf  = scr + 524288;                           // 256x1024 f32
    float* stab_h = scr + 786432;                           // 256x1024 f32
    float* alocal = scr + 1048576;                          // 256x1024 f32
    unsigned short* xbf = (unsigned short*)(scr + 1310720); // 256x2048 bf16
    unsigned short* z_a = (unsigned short*)(scr + 1572864); // 256x1024 bf16
    unsigned short* z_b = (unsigned short*)(scr + 1703936); // 256x1024 bf16
    float* addr_inv = scr + 1835008;                        // 8
    float* gamma_ws = scr + 1835016;                        // 256
    int* kidx   = (int*)(scr + 1835272);                    // 256
    int* order  = (int*)(scr + 1835528);                    // 256
    int* ebase  = (int*)(scr + 1835784);                    // 8
    int* ecnt   = (int*)(scr + 1835792);                    // 8
    int* arrive = (int*)(scr + 1835800);                    // 8

    addr_norm_k<<<1, 256, 0, stream>>>(addr, addr_inv);
    sample_k<<<BATCH, 256, 0, stream>>>(h, fib_s, fib_e, tok, opemb, num_w, num_b, addr,
                                        fs_w, fs_b, fe_w, fe_b, c1w, c1b, c2w, c2b,
                                        addr_inv, xcat, xbf, gamma_ws, kidx, out_pi);
    group_k<<<1, 256, 0, stream>>>(kidx, order, ebase, ecnt, arrive);

    // fused DEQ: 7 experts x 16 slices, 132 KB dynamic LDS (W-slice resident)
    static const int DEQ_LDS = 131072 + 1024;
    hipFuncSetAttribute((const void*)deq_k, hipFuncAttributeMaxDynamicSharedMemorySize, DEQ_LDS);
    deq_k<<<KG * 16, 256, DEQ_LDS, stream>>>(xbf, Um, Vm, Wm, c_buf, z_a, z_b,
                                             order, ebase, ecnt, arrive);

    lin_k<<<dim3(8, 16), 256, 0, stream>>>(xcat, 2048, s1w, 2048, s1b, stab_h, DIM, 1);
    lin_k<<<dim3(8, 16), 256, 0, stream>>>(stab_h, 1024, s2w, 1024, s2b, alocal, DIM, 2);
    hnext_k<<<1024, 256, 0, stream>>>(xcat, alocal, z_b, gamma_ws, out_h);
    dec_k<<<VOCAB / 64, 256, 0, stream>>>(out_h, dec_w, dec_b, out_logits);
}